// Round 10
// baseline (269.769 us; speedup 1.0000x reference)
//
#include <hip/hip_runtime.h>
#include <hip/hip_bf16.h>

#define HID 256
#define HEADS 8
#define HDIM 32
#define BATCH 2
#define SEQ 2048
#define MROWS (BATCH*SEQ)   // 4096
#define SCALE 0.17677669529663687f

typedef __attribute__((ext_vector_type(8))) short short8;   // 8 bf16 (4 VGPRs)
typedef __attribute__((ext_vector_type(4))) float f32x4;
typedef __attribute__((ext_vector_type(4))) unsigned uint4v;

static __device__ __forceinline__ unsigned short f2bf(float x) {
    __hip_bfloat16 h = __float2bfloat16(x);
    return __builtin_bit_cast(unsigned short, h);
}
static __device__ __forceinline__ unsigned cvtpk(float lo, float hi) {
    unsigned r;
    asm("v_cvt_pk_bf16_f32 %0, %1, %2" : "=v"(r) : "v"(lo), "v"(hi));
    return r;
}

// ---------------------------------------------------------------------------
// Mask dtype detection: scan first 1MB as u32 words (byte-mask at 5% density
// produces out-of-set words w.p. ~1).  flag!=0 => byte mask.
// ---------------------------------------------------------------------------
__global__ __launch_bounds__(256) void detect_mask(const unsigned* __restrict__ m,
                                                   unsigned* __restrict__ flag)
{
    unsigned bad = 0;
    for (size_t i = (size_t)blockIdx.x * 256 + threadIdx.x; i < 262144u;
         i += (size_t)gridDim.x * 256) {
        const unsigned wv = m[i];
        if (wv != 0u && wv != 1u && wv != 0x3F800000u) bad = 1;
    }
    if (__ballot(bad)) {
        if ((threadIdx.x & 63) == 0) atomicOr(flag, 1u);
    }
}

// ---------------------------------------------------------------------------
// All weight transposes in ONE launch: W[K][N] fp32 -> Wt[N][K] bf16.
// ---------------------------------------------------------------------------
__global__ __launch_bounds__(256) void tconv_all(
    const float* __restrict__ Wq, const float* __restrict__ Wk,
    const float* __restrict__ Wv, const float* __restrict__ Wo,
    const float* __restrict__ W1, const float* __restrict__ W2,
    __hip_bfloat16* __restrict__ Wtqkv, __hip_bfloat16* __restrict__ Wto,
    __hip_bfloat16* __restrict__ Wt1,   __hip_bfloat16* __restrict__ Wt2)
{
    const int t = blockIdx.x;
    const float* W; __hip_bfloat16* Wt; int K, N, tt;
    if      (t < 64)  { W = Wq; Wt = Wtqkv;          K = 256;  N = 256;  tt = t; }
    else if (t < 128) { W = Wk; Wt = Wtqkv + 65536;  K = 256;  N = 256;  tt = t - 64; }
    else if (t < 192) { W = Wv; Wt = Wtqkv + 131072; K = 256;  N = 256;  tt = t - 128; }
    else if (t < 256) { W = Wo; Wt = Wto;            K = 256;  N = 256;  tt = t - 192; }
    else if (t < 512) { W = W1; Wt = Wt1;            K = 256;  N = 1024; tt = t - 256; }
    else              { W = W2; Wt = Wt2;            K = 1024; N = 256;  tt = t - 512; }
    const int nt = N >> 5;
    const int n0 = (tt % nt) * 32, k0 = (tt / nt) * 32;
    __shared__ float tle[32][33];
    const int tx = threadIdx.x & 31, ty = threadIdx.x >> 5;
#pragma unroll
    for (int i = 0; i < 4; ++i)
        tle[ty + i*8][tx] = W[(size_t)(k0 + ty + i*8) * N + n0 + tx];
    __syncthreads();
#pragma unroll
    for (int i = 0; i < 4; ++i)
        Wt[(size_t)(n0 + ty + i*8) * K + k0 + tx] = __float2bfloat16(tle[tx][ty + i*8]);
}

// ---------------------------------------------------------------------------
// LayerNorm, wave-per-row: 4 rows/block, float4 loads, shfl reductions.
// ---------------------------------------------------------------------------
__global__ __launch_bounds__(256) void ln_wave(const float* __restrict__ in,
                                               const float* __restrict__ g,
                                               const float* __restrict__ b,
                                               __hip_bfloat16* __restrict__ out)
{
    const int wave = threadIdx.x >> 6, lane = threadIdx.x & 63;
    const int row = blockIdx.x * 4 + wave;
    const float4 v = ((const float4*)(in + ((size_t)row << 8)))[lane];
    float s = v.x + v.y + v.z + v.w;
    for (int o = 32; o; o >>= 1) s += __shfl_xor(s, o);
    const float m = s * (1.f/HID);
    const float4 dv = make_float4(v.x - m, v.y - m, v.z - m, v.w - m);
    float vs = dv.x*dv.x + dv.y*dv.y + dv.z*dv.z + dv.w*dv.w;
    for (int o = 32; o; o >>= 1) vs += __shfl_xor(vs, o);
    const float rstd = rsqrtf(vs * (1.f/HID) + 1e-5f);
    const float4 gv = ((const float4*)g)[lane];
    const float4 bv = ((const float4*)b)[lane];
    ushort4 o4;
    o4.x = f2bf(dv.x * rstd * gv.x + bv.x);
    o4.y = f2bf(dv.y * rstd * gv.y + bv.y);
    o4.z = f2bf(dv.z * rstd * gv.z + bv.z);
    o4.w = f2bf(dv.w * rstd * gv.w + bv.w);
    ((ushort4*)(out + ((size_t)row << 8)))[lane] = o4;
}

// ---------------------------------------------------------------------------
// Fused QKV MFMA GEMM -> bf16 attention operands:
//   Q (b,h,s,d) bf16 PRE-SCALED by 1/sqrt(D);  K (b,h,s,d);  Vt (b,h,d,s).
// ---------------------------------------------------------------------------
__global__ __launch_bounds__(256) void gemm_qkv(const __hip_bfloat16* __restrict__ A,
                                                const __hip_bfloat16* __restrict__ Wt,
                                                const float* __restrict__ bq,
                                                const float* __restrict__ bk,
                                                const float* __restrict__ bv,
                                                __hip_bfloat16* __restrict__ qh,
                                                __hip_bfloat16* __restrict__ kh,
                                                __hip_bfloat16* __restrict__ vt)
{
    const int tid = threadIdx.x;
    const int wv = tid >> 6, lane = tid & 63;
    const int wr = wv >> 1, wc = wv & 1;
    const int r0 = blockIdx.x * 64 + wr * 32;
    const int c0 = blockIdx.y * 64 + wc * 32;
    const int al = lane & 15, ah = lane >> 4;

    f32x4 acc[2][2] = {};
    const short8* Ap[2];
    const short8* Bp[2];
#pragma unroll
    for (int m = 0; m < 2; ++m)
        Ap[m] = (const short8*)(A + (size_t)(r0 + m*16 + al) * 256 + ah * 8);
#pragma unroll
    for (int n = 0; n < 2; ++n)
        Bp[n] = (const short8*)(Wt + (size_t)(c0 + n*16 + al) * 256 + ah * 8);

#pragma unroll 8
    for (int kt = 0; kt < 8; ++kt) {
        short8 af[2], bf[2];
#pragma unroll
        for (int m = 0; m < 2; ++m) af[m] = Ap[m][kt*4];
#pragma unroll
        for (int n = 0; n < 2; ++n) bf[n] = Bp[n][kt*4];
#pragma unroll
        for (int m = 0; m < 2; ++m)
#pragma unroll
            for (int n = 0; n < 2; ++n)
                acc[m][n] = __builtin_amdgcn_mfma_f32_16x16x32_bf16(
                    af[m], bf[n], acc[m][n], 0, 0, 0);
    }

#pragma unroll
    for (int m = 0; m < 2; ++m)
#pragma unroll
        for (int n = 0; n < 2; ++n) {
            const int col = c0 + n*16 + al;
            const int which = col >> 8, cc = col & 255;
            const int h = cc >> 5, d = cc & 31;
            const float* bp = which == 0 ? bq : (which == 1 ? bk : bv);
            const float bvv = bp[cc];
            const int row0 = r0 + m*16 + ah*4;
            const int bb = row0 >> 11, s0 = row0 & 2047;
            if (which == 2) {
                ushort4 o4;
                o4.x = f2bf(acc[m][n][0] + bvv);
                o4.y = f2bf(acc[m][n][1] + bvv);
                o4.z = f2bf(acc[m][n][2] + bvv);
                o4.w = f2bf(acc[m][n][3] + bvv);
                *(ushort4*)(vt + ((size_t)((bb*8 + h)*32 + d) << 11) + s0) = o4;
            } else {
                __hip_bfloat16* op = which == 0 ? qh : kh;
                const float sc = which == 0 ? SCALE : 1.f;
#pragma unroll
                for (int r = 0; r < 4; ++r) {
                    const float v = (acc[m][n][r] + bvv) * sc;
                    op[(((size_t)(bb*8 + h) << 11) + s0 + r) * 32 + d] =
                        __float2bfloat16(v);
                }
            }
        }
}

// ---------------------------------------------------------------------------
// Dense masked flash attention, k-split x2 for occupancy. Wave wid:
// tile = wid>>1 (b,h,16-q tile), ks = wid&1 -> keys [ks*1024, ks*1024+1024).
// Writes f32 partial O^T frags + partial lsum; attn_comb merges.
// ---------------------------------------------------------------------------
__global__ __launch_bounds__(256) void attn_part(const __hip_bfloat16* __restrict__ Qh,
                                                 const __hip_bfloat16* __restrict__ Kh,
                                                 const __hip_bfloat16* __restrict__ Vt,
                                                 const void* __restrict__ mask,
                                                 const unsigned* __restrict__ flag,
                                                 float* __restrict__ part_o,
                                                 float* __restrict__ part_l)
{
    const int wave = threadIdx.x >> 6, lane = threadIdx.x & 63;
    const int wid = blockIdx.x * 4 + wave;       // 4096 waves
    const int tile = wid >> 1, ks = wid & 1;
    const int bh = tile >> 7, qt = tile & 127;
    const int b = bh >> 3;
    const int q0 = qt << 4;
    const int qi = lane & 15, g = lane >> 4;
    const int bytemode = (*flag != 0);
    const int kbeg = ks << 10;

    const short8 qf = *(const short8*)(Qh + (((size_t)bh << 11) + q0 + qi) * 32 + g*8);

    const __hip_bfloat16* Kb = Kh + ((size_t)bh << 16);
    const __hip_bfloat16* Vb = Vt + ((size_t)bh << 16);
    const unsigned char* mb = (const unsigned char*)mask
                            + (((size_t)b << 11) + q0 + qi) * 2048;
    const unsigned* mw = (const unsigned*)mask
                       + (((size_t)b << 11) + q0 + qi) * 2048;

    const int slA = ((2*g) & 3) * 16 + qi;       // src lane for B-frag w0,w1
    const int slB = ((2*g + 1) & 3) * 16 + qi;   // src lane for w2,w3
    const bool hi = g >= 2;

    f32x4 o0 = {}, o1 = {};
    const f32x4 zero = {};
    float lsum = 0.f;

    for (int k0 = kbeg; k0 < kbeg + 1024; k0 += 32) {
        const short8 kf0 = *(const short8*)(Kb + ((size_t)(k0      + qi) << 5) + g*8);
        const short8 kf1 = *(const short8*)(Kb + ((size_t)(k0 + 16 + qi) << 5) + g*8);
        const short8 vf0 = *(const short8*)(Vb + ((size_t) qi       << 11) + k0 + g*8);
        const short8 vf1 = *(const short8*)(Vb + ((size_t)(qi + 16) << 11) + k0 + g*8);

        f32x4 s0 = __builtin_amdgcn_mfma_f32_16x16x32_bf16(kf0, qf, zero, 0, 0, 0);
        f32x4 s1 = __builtin_amdgcn_mfma_f32_16x16x32_bf16(kf1, qf, zero, 0, 0, 0);

        float p0[4], p1[4];
        if (bytemode) {
            const unsigned m0 = *(const unsigned*)(mb + k0 + 4*g);
            const unsigned m1 = *(const unsigned*)(mb + k0 + 16 + 4*g);
#pragma unroll
            for (int r = 0; r < 4; ++r) {
                p0[r] = ((m0 >> (8*r)) & 255u) ? __expf(s0[r]) : 0.f;
                p1[r] = ((m1 >> (8*r)) & 255u) ? __expf(s1[r]) : 0.f;
            }
        } else {
            const uint4v m0 = *(const uint4v*)(mw + k0 + 4*g);
            const uint4v m1 = *(const uint4v*)(mw + k0 + 16 + 4*g);
#pragma unroll
            for (int r = 0; r < 4; ++r) {
                p0[r] = m0[r] ? __expf(s0[r]) : 0.f;
                p1[r] = m1[r] ? __expf(s1[r]) : 0.f;
            }
        }
        lsum += ((p0[0] + p0[1]) + (p0[2] + p0[3]))
              + ((p1[0] + p1[1]) + (p1[2] + p1[3]));

        const unsigned f0w0 = cvtpk(p0[0], p0[1]), f0w1 = cvtpk(p0[2], p0[3]);
        const unsigned f1w0 = cvtpk(p1[0], p1[1]), f1w1 = cvtpk(p1[2], p1[3]);

        const unsigned aw0 = __shfl(f0w0, slA), aw1 = __shfl(f0w1, slA);
        const unsigned aw2 = __shfl(f0w0, slB), aw3 = __shfl(f0w1, slB);
        const unsigned cw0 = __shfl(f1w0, slA), cw1 = __shfl(f1w1, slA);
        const unsigned cw2 = __shfl(f1w0, slB), cw3 = __shfl(f1w1, slB);
        uint4v pw;
        pw[0] = hi ? cw0 : aw0;
        pw[1] = hi ? cw1 : aw1;
        pw[2] = hi ? cw2 : aw2;
        pw[3] = hi ? cw3 : aw3;
        const short8 pb = __builtin_bit_cast(short8, pw);

        o0 = __builtin_amdgcn_mfma_f32_16x16x32_bf16(vf0, pb, o0, 0, 0, 0);
        o1 = __builtin_amdgcn_mfma_f32_16x16x32_bf16(vf1, pb, o1, 0, 0, 0);
    }

    // partial lsum: sum the 4 lane-groups sharing qi
    lsum += __shfl_xor(lsum, 16);
    lsum += __shfl_xor(lsum, 32);

    // write partial O^T frags (f32): [wid][q=qi][d = 4g+r | 16+4g+r]
    float* po = part_o + ((size_t)wid << 9) + qi*32 + 4*g;
    *(f32x4*)(po)      = o0;
    *(f32x4*)(po + 16) = o1;
    if (g == 0) part_l[(wid << 4) + qi] = lsum;
}

// ---------------------------------------------------------------------------
// Merge 2 k-slices, normalize, emit bf16 attn (b, q, h*32+d) rows.
// ---------------------------------------------------------------------------
__global__ __launch_bounds__(256) void attn_comb(const float* __restrict__ part_o,
                                                 const float* __restrict__ part_l,
                                                 __hip_bfloat16* __restrict__ out)
{
    const int e = blockIdx.x * 256 + threadIdx.x;   // 2048 tiles x 512
    const int tile = e >> 9, j = e & 511;
    const int q = j >> 5, d = j & 31;
    const float a = part_o[((size_t)(tile*2) << 9) + j]
                  + part_o[((size_t)(tile*2+1) << 9) + j];
    const float l = part_l[((tile*2) << 4) + q] + part_l[((tile*2+1) << 4) + q];
    const int bh = tile >> 7, qt = tile & 127;
    const int b = bh >> 3, h = bh & 7;
    out[(((size_t)b << 11) + qt*16 + q) * 256 + h*32 + d] = __float2bfloat16(a / l);
}

// ---------------------------------------------------------------------------
// bf16 MFMA GEMM (Wo/W1/W2), wave tile 16x32 (2x waves vs 32x32).
// EPI 1: +res -> fp32.  EPI 2: GELU -> bf16.
// ---------------------------------------------------------------------------
template<int KTOT, int EPI>
__global__ __launch_bounds__(256) void gemm_mfma(const __hip_bfloat16* __restrict__ A,
                                                 const __hip_bfloat16* __restrict__ Wt,
                                                 const float* __restrict__ bias,
                                                 const float* __restrict__ res,
                                                 float* __restrict__ outF,
                                                 __hip_bfloat16* __restrict__ outB,
                                                 int N)
{
    const int tid = threadIdx.x;
    const int wv = tid >> 6, lane = tid & 63;
    const int r0 = blockIdx.x * 64 + wv * 16;
    const int c0 = blockIdx.y * 32;
    const int al = lane & 15, ah = lane >> 4;

    f32x4 acc[2] = {};
    const short8* Ap = (const short8*)(A + (size_t)(r0 + al) * KTOT + ah * 8);
    const short8* Bp[2];
#pragma unroll
    for (int n = 0; n < 2; ++n)
        Bp[n] = (const short8*)(Wt + (size_t)(c0 + n*16 + al) * KTOT + ah * 8);

#pragma unroll 8
    for (int kt = 0; kt < KTOT/32; ++kt) {
        const short8 af = Ap[kt*4];
        short8 bf[2];
#pragma unroll
        for (int n = 0; n < 2; ++n) bf[n] = Bp[n][kt*4];
#pragma unroll
        for (int n = 0; n < 2; ++n)
            acc[n] = __builtin_amdgcn_mfma_f32_16x16x32_bf16(af, bf[n], acc[n], 0, 0, 0);
    }

#pragma unroll
    for (int n = 0; n < 2; ++n) {
        const int col = c0 + n*16 + al;
        const float bv = bias[col];
#pragma unroll
        for (int r = 0; r < 4; ++r) {
            const int row = r0 + ah*4 + r;
            const float v = acc[n][r] + bv;
            const size_t o = (size_t)row * N + col;
            if (EPI == 1) {
                outF[o] = v + res[o];
            } else {
                outB[o] = __float2bfloat16(
                    0.5f * v * (1.0f + erff(v * 0.70710678118654752f)));
            }
        }
    }
}

// ---------------------------------------------------------------------------
extern "C" void kernel_launch(void* const* d_in, const int* in_sizes, int n_in,
                              void* d_out, int out_size, void* d_ws, size_t ws_size,
                              hipStream_t stream)
{
    const float* x    = (const float*)d_in[0];
    const void*  mask = d_in[1];
    const float* ln1g = (const float*)d_in[2];
    const float* ln1b = (const float*)d_in[3];
    const float* ln2g = (const float*)d_in[4];
    const float* ln2b = (const float*)d_in[5];
    const float* Wq   = (const float*)d_in[6];
    const float* bq   = (const float*)d_in[7];
    const float* Wk   = (const float*)d_in[8];
    const float* bk   = (const float*)d_in[9];
    const float* Wv   = (const float*)d_in[10];
    const float* bv   = (const float*)d_in[11];
    const float* Wo   = (const float*)d_in[12];
    const float* bo   = (const float*)d_in[13];
    const float* W1   = (const float*)d_in[14];
    const float* b1   = (const float*)d_in[15];
    const float* W2   = (const float*)d_in[16];
    const float* b2   = (const float*)d_in[17];

    // Workspace (~26.1 MB). part_o/part_l alias hbuf + head of x1:
    //   attn_part writes -> attn_comb reads -> (Wo writes x1, W1 writes hbuf)
    char* w = (char*)d_ws;
    unsigned* flag        = (unsigned*)(w);                        // 4 B
    __hip_bfloat16* qh    = (__hip_bfloat16*)(w + 4096);           // 2 MB
    __hip_bfloat16* kh    = qh  + (size_t)MROWS * HID;             // 2 MB
    __hip_bfloat16* vt    = kh  + (size_t)MROWS * HID;             // 2 MB
    __hip_bfloat16* nx    = vt  + (size_t)MROWS * HID;             // 2 MB
    __hip_bfloat16* attn_b= nx  + (size_t)MROWS * HID;             // 2 MB
    __hip_bfloat16* nx2   = attn_b + (size_t)MROWS * HID;          // 2 MB
    __hip_bfloat16* hbuf  = nx2 + (size_t)MROWS * HID;             // 8 MB
    float* x1             = (float*)(hbuf + (size_t)MROWS * 4*HID);// 4 MB
    __hip_bfloat16* Wtqkv = (__hip_bfloat16*)(x1 + (size_t)MROWS * HID);
    __hip_bfloat16* Wto   = Wtqkv + 196608;                        // [256][256]
    __hip_bfloat16* Wt1   = Wto + 65536;                           // [1024][256]
    __hip_bfloat16* Wt2   = Wt1 + 262144;                          // [256][1024]
    float* part_o = (float*)hbuf;                 // 4096x512 f32 = 8 MB (alias)
    float* part_l = part_o + (size_t)4096 * 512;  // 256 KB (head of x1, alias)
    float* ob   = (float*)d_out;

    hipMemsetAsync(flag, 0, 4, stream);
    detect_mask<<<128, 256, 0, stream>>>((const unsigned*)mask, flag);
    tconv_all<<<768, 256, 0, stream>>>(Wq, Wk, Wv, Wo, W1, W2, Wtqkv, Wto, Wt1, Wt2);
    ln_wave<<<MROWS/4, 256, 0, stream>>>(x, ln1g, ln1b, nx);
    gemm_qkv<<<dim3(64,12), 256, 0, stream>>>(nx, Wtqkv, bq, bk, bv, qh, kh, vt);
    attn_part<<<1024, 256, 0, stream>>>(qh, kh, vt, mask, flag, part_o, part_l);
    attn_comb<<<4096, 256, 0, stream>>>(part_o, part_l, attn_b);
    gemm_mfma<256,1><<<dim3(64,8), 256, 0, stream>>>(attn_b, Wto, bo, x, x1, nullptr, HID);
    ln_wave<<<MROWS/4, 256, 0, stream>>>(x1, ln2g, ln2b, nx2);
    gemm_mfma<256,2><<<dim3(64,32), 256, 0, stream>>>(nx2, Wt1, b1, nullptr, nullptr, hbuf, 4*HID);
    gemm_mfma<1024,1><<<dim3(64,8), 256, 0, stream>>>(hbuf, Wt2, b2, x1, ob, nullptr, HID);
}

// Round 11
// 259.464 us; speedup vs baseline: 1.0397x; 1.0397x over previous
//
#include <hip/hip_runtime.h>
#include <hip/hip_bf16.h>

#define HID 256
#define HEADS 8
#define HDIM 32
#define BATCH 2
#define SEQ 2048
#define MROWS (BATCH*SEQ)   // 4096
#define SCALE 0.17677669529663687f

typedef __attribute__((ext_vector_type(8))) short short8;   // 8 bf16 (4 VGPRs)
typedef __attribute__((ext_vector_type(4))) float f32x4;
typedef __attribute__((ext_vector_type(4))) unsigned uint4v;

static __device__ __forceinline__ unsigned short f2bf(float x) {
    __hip_bfloat16 h = __float2bfloat16(x);
    return __builtin_bit_cast(unsigned short, h);
}
static __device__ __forceinline__ unsigned cvtpk(float lo, float hi) {
    unsigned r;
    asm("v_cvt_pk_bf16_f32 %0, %1, %2" : "=v"(r) : "v"(lo), "v"(hi));
    return r;
}

// ---------------------------------------------------------------------------
// Mask dtype detection: scan first 1MB as u32 words. flag!=0 => byte mask.
// ---------------------------------------------------------------------------
__global__ __launch_bounds__(256) void detect_mask(const unsigned* __restrict__ m,
                                                   unsigned* __restrict__ flag)
{
    unsigned bad = 0;
    for (size_t i = (size_t)blockIdx.x * 256 + threadIdx.x; i < 262144u;
         i += (size_t)gridDim.x * 256) {
        const unsigned wv = m[i];
        if (wv != 0u && wv != 1u && wv != 0x3F800000u) bad = 1;
    }
    if (__ballot(bad)) {
        if ((threadIdx.x & 63) == 0) atomicOr(flag, 1u);
    }
}

// ---------------------------------------------------------------------------
// All weight transposes in ONE launch: W[K][N] fp32 -> Wt[N][K] bf16.
// ---------------------------------------------------------------------------
__global__ __launch_bounds__(256) void tconv_all(
    const float* __restrict__ Wq, const float* __restrict__ Wk,
    const float* __restrict__ Wv, const float* __restrict__ Wo,
    const float* __restrict__ W1, const float* __restrict__ W2,
    __hip_bfloat16* __restrict__ Wtqkv, __hip_bfloat16* __restrict__ Wto,
    __hip_bfloat16* __restrict__ Wt1,   __hip_bfloat16* __restrict__ Wt2)
{
    const int t = blockIdx.x;
    const float* W; __hip_bfloat16* Wt; int K, N, tt;
    if      (t < 64)  { W = Wq; Wt = Wtqkv;          K = 256;  N = 256;  tt = t; }
    else if (t < 128) { W = Wk; Wt = Wtqkv + 65536;  K = 256;  N = 256;  tt = t - 64; }
    else if (t < 192) { W = Wv; Wt = Wtqkv + 131072; K = 256;  N = 256;  tt = t - 128; }
    else if (t < 256) { W = Wo; Wt = Wto;            K = 256;  N = 256;  tt = t - 192; }
    else if (t < 512) { W = W1; Wt = Wt1;            K = 256;  N = 1024; tt = t - 256; }
    else              { W = W2; Wt = Wt2;            K = 1024; N = 256;  tt = t - 512; }
    const int nt = N >> 5;
    const int n0 = (tt % nt) * 32, k0 = (tt / nt) * 32;
    __shared__ float tle[32][33];
    const int tx = threadIdx.x & 31, ty = threadIdx.x >> 5;
#pragma unroll
    for (int i = 0; i < 4; ++i)
        tle[ty + i*8][tx] = W[(size_t)(k0 + ty + i*8) * N + n0 + tx];
    __syncthreads();
#pragma unroll
    for (int i = 0; i < 4; ++i)
        Wt[(size_t)(n0 + ty + i*8) * K + k0 + tx] = __float2bfloat16(tle[tx][ty + i*8]);
}

// ---------------------------------------------------------------------------
// LayerNorm, wave-per-row: 4 rows/block, float4 loads, shfl reductions.
// ---------------------------------------------------------------------------
__global__ __launch_bounds__(256) void ln_wave(const float* __restrict__ in,
                                               const float* __restrict__ g,
                                               const float* __restrict__ b,
                                               __hip_bfloat16* __restrict__ out)
{
    const int wave = threadIdx.x >> 6, lane = threadIdx.x & 63;
    const int row = blockIdx.x * 4 + wave;
    const float4 v = ((const float4*)(in + ((size_t)row << 8)))[lane];
    float s = v.x + v.y + v.z + v.w;
    for (int o = 32; o; o >>= 1) s += __shfl_xor(s, o);
    const float m = s * (1.f/HID);
    const float4 dv = make_float4(v.x - m, v.y - m, v.z - m, v.w - m);
    float vs = dv.x*dv.x + dv.y*dv.y + dv.z*dv.z + dv.w*dv.w;
    for (int o = 32; o; o >>= 1) vs += __shfl_xor(vs, o);
    const float rstd = rsqrtf(vs * (1.f/HID) + 1e-5f);
    const float4 gv = ((const float4*)g)[lane];
    const float4 bv = ((const float4*)b)[lane];
    ushort4 o4;
    o4.x = f2bf(dv.x * rstd * gv.x + bv.x);
    o4.y = f2bf(dv.y * rstd * gv.y + bv.y);
    o4.z = f2bf(dv.z * rstd * gv.z + bv.z);
    o4.w = f2bf(dv.w * rstd * gv.w + bv.w);
    ((ushort4*)(out + ((size_t)row << 8)))[lane] = o4;
}

// ---------------------------------------------------------------------------
// Fused QKV MFMA GEMM -> bf16 attention operands:
//   Q (b,h,s,d) bf16 PRE-SCALED by 1/sqrt(D);  K (b,h,s,d);  Vt (b,h,d,s).
// ---------------------------------------------------------------------------
__global__ __launch_bounds__(256) void gemm_qkv(const __hip_bfloat16* __restrict__ A,
                                                const __hip_bfloat16* __restrict__ Wt,
                                                const float* __restrict__ bq,
                                                const float* __restrict__ bk,
                                                const float* __restrict__ bv,
                                                __hip_bfloat16* __restrict__ qh,
                                                __hip_bfloat16* __restrict__ kh,
                                                __hip_bfloat16* __restrict__ vt)
{
    const int tid = threadIdx.x;
    const int wv = tid >> 6, lane = tid & 63;
    const int wr = wv >> 1, wc = wv & 1;
    const int r0 = blockIdx.x * 64 + wr * 32;
    const int c0 = blockIdx.y * 64 + wc * 32;
    const int al = lane & 15, ah = lane >> 4;

    f32x4 acc[2][2] = {};
    const short8* Ap[2];
    const short8* Bp[2];
#pragma unroll
    for (int m = 0; m < 2; ++m)
        Ap[m] = (const short8*)(A + (size_t)(r0 + m*16 + al) * 256 + ah * 8);
#pragma unroll
    for (int n = 0; n < 2; ++n)
        Bp[n] = (const short8*)(Wt + (size_t)(c0 + n*16 + al) * 256 + ah * 8);

#pragma unroll 8
    for (int kt = 0; kt < 8; ++kt) {
        short8 af[2], bf[2];
#pragma unroll
        for (int m = 0; m < 2; ++m) af[m] = Ap[m][kt*4];
#pragma unroll
        for (int n = 0; n < 2; ++n) bf[n] = Bp[n][kt*4];
#pragma unroll
        for (int m = 0; m < 2; ++m)
#pragma unroll
            for (int n = 0; n < 2; ++n)
                acc[m][n] = __builtin_amdgcn_mfma_f32_16x16x32_bf16(
                    af[m], bf[n], acc[m][n], 0, 0, 0);
    }

#pragma unroll
    for (int m = 0; m < 2; ++m)
#pragma unroll
        for (int n = 0; n < 2; ++n) {
            const int col = c0 + n*16 + al;
            const int which = col >> 8, cc = col & 255;
            const int h = cc >> 5, d = cc & 31;
            const float* bp = which == 0 ? bq : (which == 1 ? bk : bv);
            const float bvv = bp[cc];
            const int row0 = r0 + m*16 + ah*4;
            const int bb = row0 >> 11, s0 = row0 & 2047;
            if (which == 2) {
                ushort4 o4;
                o4.x = f2bf(acc[m][n][0] + bvv);
                o4.y = f2bf(acc[m][n][1] + bvv);
                o4.z = f2bf(acc[m][n][2] + bvv);
                o4.w = f2bf(acc[m][n][3] + bvv);
                *(ushort4*)(vt + ((size_t)((bb*8 + h)*32 + d) << 11) + s0) = o4;
            } else {
                __hip_bfloat16* op = which == 0 ? qh : kh;
                const float sc = which == 0 ? SCALE : 1.f;
#pragma unroll
                for (int r = 0; r < 4; ++r) {
                    const float v = (acc[m][n][r] + bvv) * sc;
                    op[(((size_t)(bb*8 + h) << 11) + s0 + r) * 32 + d] =
                        __float2bfloat16(v);
                }
            }
        }
}

// ---------------------------------------------------------------------------
// Dense masked flash attention, k-split x4. Wave wid: tile = wid>>2 (b,h,
// 16-q tile), ks = wid&3 -> keys [ks*512, ks*512+512). Partials -> attn_comb.
// ---------------------------------------------------------------------------
__global__ __launch_bounds__(256) void attn_part(const __hip_bfloat16* __restrict__ Qh,
                                                 const __hip_bfloat16* __restrict__ Kh,
                                                 const __hip_bfloat16* __restrict__ Vt,
                                                 const void* __restrict__ mask,
                                                 const unsigned* __restrict__ flag,
                                                 float* __restrict__ part_o,
                                                 float* __restrict__ part_l)
{
    const int wave = threadIdx.x >> 6, lane = threadIdx.x & 63;
    const int wid = blockIdx.x * 4 + wave;       // 8192 waves
    const int tile = wid >> 2, ks = wid & 3;
    const int bh = tile >> 7, qt = tile & 127;
    const int b = bh >> 3;
    const int q0 = qt << 4;
    const int qi = lane & 15, g = lane >> 4;
    const int bytemode = (*flag != 0);
    const int kbeg = ks << 9;

    const short8 qf = *(const short8*)(Qh + (((size_t)bh << 11) + q0 + qi) * 32 + g*8);

    const __hip_bfloat16* Kb = Kh + ((size_t)bh << 16);
    const __hip_bfloat16* Vb = Vt + ((size_t)bh << 16);
    const unsigned char* mb = (const unsigned char*)mask
                            + (((size_t)b << 11) + q0 + qi) * 2048;
    const unsigned* mw = (const unsigned*)mask
                       + (((size_t)b << 11) + q0 + qi) * 2048;

    const int slA = ((2*g) & 3) * 16 + qi;       // src lane for B-frag w0,w1
    const int slB = ((2*g + 1) & 3) * 16 + qi;   // src lane for w2,w3
    const bool hi = g >= 2;

    f32x4 o0 = {}, o1 = {};
    const f32x4 zero = {};
    float lsum = 0.f;

    for (int k0 = kbeg; k0 < kbeg + 512; k0 += 32) {
        const short8 kf0 = *(const short8*)(Kb + ((size_t)(k0      + qi) << 5) + g*8);
        const short8 kf1 = *(const short8*)(Kb + ((size_t)(k0 + 16 + qi) << 5) + g*8);
        const short8 vf0 = *(const short8*)(Vb + ((size_t) qi       << 11) + k0 + g*8);
        const short8 vf1 = *(const short8*)(Vb + ((size_t)(qi + 16) << 11) + k0 + g*8);

        f32x4 s0 = __builtin_amdgcn_mfma_f32_16x16x32_bf16(kf0, qf, zero, 0, 0, 0);
        f32x4 s1 = __builtin_amdgcn_mfma_f32_16x16x32_bf16(kf1, qf, zero, 0, 0, 0);

        float p0[4], p1[4];
        if (bytemode) {
            const unsigned m0 = *(const unsigned*)(mb + k0 + 4*g);
            const unsigned m1 = *(const unsigned*)(mb + k0 + 16 + 4*g);
#pragma unroll
            for (int r = 0; r < 4; ++r) {
                p0[r] = ((m0 >> (8*r)) & 255u) ? __expf(s0[r]) : 0.f;
                p1[r] = ((m1 >> (8*r)) & 255u) ? __expf(s1[r]) : 0.f;
            }
        } else {
            const uint4v m0 = *(const uint4v*)(mw + k0 + 4*g);
            const uint4v m1 = *(const uint4v*)(mw + k0 + 16 + 4*g);
#pragma unroll
            for (int r = 0; r < 4; ++r) {
                p0[r] = m0[r] ? __expf(s0[r]) : 0.f;
                p1[r] = m1[r] ? __expf(s1[r]) : 0.f;
            }
        }
        lsum += ((p0[0] + p0[1]) + (p0[2] + p0[3]))
              + ((p1[0] + p1[1]) + (p1[2] + p1[3]));

        const unsigned f0w0 = cvtpk(p0[0], p0[1]), f0w1 = cvtpk(p0[2], p0[3]);
        const unsigned f1w0 = cvtpk(p1[0], p1[1]), f1w1 = cvtpk(p1[2], p1[3]);

        const unsigned aw0 = __shfl(f0w0, slA), aw1 = __shfl(f0w1, slA);
        const unsigned aw2 = __shfl(f0w0, slB), aw3 = __shfl(f0w1, slB);
        const unsigned cw0 = __shfl(f1w0, slA), cw1 = __shfl(f1w1, slA);
        const unsigned cw2 = __shfl(f1w0, slB), cw3 = __shfl(f1w1, slB);
        uint4v pw;
        pw[0] = hi ? cw0 : aw0;
        pw[1] = hi ? cw1 : aw1;
        pw[2] = hi ? cw2 : aw2;
        pw[3] = hi ? cw3 : aw3;
        const short8 pb = __builtin_bit_cast(short8, pw);

        o0 = __builtin_amdgcn_mfma_f32_16x16x32_bf16(vf0, pb, o0, 0, 0, 0);
        o1 = __builtin_amdgcn_mfma_f32_16x16x32_bf16(vf1, pb, o1, 0, 0, 0);
    }

    lsum += __shfl_xor(lsum, 16);
    lsum += __shfl_xor(lsum, 32);

    float* po = part_o + ((size_t)wid << 9) + qi*32 + 4*g;
    *(f32x4*)(po)      = o0;
    *(f32x4*)(po + 16) = o1;
    if (g == 0) part_l[(wid << 4) + qi] = lsum;
}

// ---------------------------------------------------------------------------
// Merge 4 k-slices, normalize, emit bf16 attn (b, q, h*32+d) rows.
// ---------------------------------------------------------------------------
__global__ __launch_bounds__(256) void attn_comb(const float* __restrict__ part_o,
                                                 const float* __restrict__ part_l,
                                                 __hip_bfloat16* __restrict__ out)
{
    const int e = blockIdx.x * 256 + threadIdx.x;   // 2048 tiles x 512
    const int tile = e >> 9, j = e & 511;
    const int q = j >> 5, d = j & 31;
    float a = 0.f, l = 0.f;
#pragma unroll
    for (int s = 0; s < 4; ++s) {
        a += part_o[((size_t)(tile*4 + s) << 9) + j];
        l += part_l[((tile*4 + s) << 4) + q];
    }
    const int bh = tile >> 7, qt = tile & 127;
    const int b = bh >> 3, h = bh & 7;
    out[(((size_t)b << 11) + qt*16 + q) * 256 + h*32 + d] = __float2bfloat16(a / l);
}

// ---------------------------------------------------------------------------
// bf16 MFMA GEMM, 4 waves, 64x64 block, 32x32 wave tile (round-9 shape).
// EPI 2: GELU -> bf16 (W1).
// ---------------------------------------------------------------------------
template<int KTOT, int EPI>
__global__ __launch_bounds__(256) void gemm_mfma(const __hip_bfloat16* __restrict__ A,
                                                 const __hip_bfloat16* __restrict__ Wt,
                                                 const float* __restrict__ bias,
                                                 const float* __restrict__ res,
                                                 float* __restrict__ outF,
                                                 __hip_bfloat16* __restrict__ outB,
                                                 int N)
{
    const int tid = threadIdx.x;
    const int wv = tid >> 6, lane = tid & 63;
    const int wr = wv >> 1, wc = wv & 1;
    const int r0 = blockIdx.x * 64 + wr * 32;
    const int c0 = blockIdx.y * 64 + wc * 32;
    const int al = lane & 15, ah = lane >> 4;

    f32x4 acc[2][2] = {};
    const short8* Ap[2];
    const short8* Bp[2];
#pragma unroll
    for (int m = 0; m < 2; ++m)
        Ap[m] = (const short8*)(A + (size_t)(r0 + m*16 + al) * KTOT + ah * 8);
#pragma unroll
    for (int n = 0; n < 2; ++n)
        Bp[n] = (const short8*)(Wt + (size_t)(c0 + n*16 + al) * KTOT + ah * 8);

#pragma unroll 8
    for (int kt = 0; kt < KTOT/32; ++kt) {
        short8 af[2], bf[2];
#pragma unroll
        for (int m = 0; m < 2; ++m) af[m] = Ap[m][kt*4];
#pragma unroll
        for (int n = 0; n < 2; ++n) bf[n] = Bp[n][kt*4];
#pragma unroll
        for (int m = 0; m < 2; ++m)
#pragma unroll
            for (int n = 0; n < 2; ++n)
                acc[m][n] = __builtin_amdgcn_mfma_f32_16x16x32_bf16(
                    af[m], bf[n], acc[m][n], 0, 0, 0);
    }

#pragma unroll
    for (int m = 0; m < 2; ++m)
#pragma unroll
        for (int n = 0; n < 2; ++n) {
            const int col = c0 + n*16 + al;
            const float bv = bias[col];
#pragma unroll
            for (int r = 0; r < 4; ++r) {
                const int row = r0 + m*16 + ah*4 + r;
                const float v = acc[m][n][r] + bv;
                const size_t o = (size_t)row * N + col;
                if (EPI == 1) {
                    outF[o] = v + res[o];
                } else {
                    outB[o] = __float2bfloat16(
                        0.5f * v * (1.0f + erff(v * 0.70710678118654752f)));
                }
            }
        }
}

// ---------------------------------------------------------------------------
// K-split GEMM for N=256 outputs (Wo, W2): 512 threads = 8 waves =
// 4 output tiles (32x32) x 2 K-halves; f32 LDS combine; +res epilogue.
// ---------------------------------------------------------------------------
template<int KTOT>
__global__ __launch_bounds__(512) void gemm_ks(const __hip_bfloat16* __restrict__ A,
                                               const __hip_bfloat16* __restrict__ Wt,
                                               const float* __restrict__ bias,
                                               const float* __restrict__ res,
                                               float* __restrict__ outF,
                                               int N)
{
    constexpr int KH = KTOT / 2;
    __shared__ float red[4][64][17];
    const int tid = threadIdx.x;
    const int wv = tid >> 6, lane = tid & 63;
    const int t = wv & 3, ks = wv >> 2;
    const int wr = t >> 1, wc = t & 1;
    const int r0 = blockIdx.x * 64 + wr * 32;
    const int c0 = blockIdx.y * 64 + wc * 32;
    const int al = lane & 15, ah = lane >> 4;

    f32x4 acc[2][2] = {};
    const short8* Ap[2];
    const short8* Bp[2];
#pragma unroll
    for (int m = 0; m < 2; ++m)
        Ap[m] = (const short8*)(A + (size_t)(r0 + m*16 + al) * KTOT + ks*KH + ah * 8);
#pragma unroll
    for (int n = 0; n < 2; ++n)
        Bp[n] = (const short8*)(Wt + (size_t)(c0 + n*16 + al) * KTOT + ks*KH + ah * 8);

#pragma unroll 8
    for (int kt = 0; kt < KH/32; ++kt) {
        short8 af[2], bf[2];
#pragma unroll
        for (int m = 0; m < 2; ++m) af[m] = Ap[m][kt*4];
#pragma unroll
        for (int n = 0; n < 2; ++n) bf[n] = Bp[n][kt*4];
#pragma unroll
        for (int m = 0; m < 2; ++m)
#pragma unroll
            for (int n = 0; n < 2; ++n)
                acc[m][n] = __builtin_amdgcn_mfma_f32_16x16x32_bf16(
                    af[m], bf[n], acc[m][n], 0, 0, 0);
    }

    if (ks == 1) {
#pragma unroll
        for (int m = 0; m < 2; ++m)
#pragma unroll
            for (int n = 0; n < 2; ++n)
#pragma unroll
                for (int r = 0; r < 4; ++r)
                    red[t][lane][(m*2 + n)*4 + r] = acc[m][n][r];
    }
    __syncthreads();
    if (ks == 0) {
#pragma unroll
        for (int m = 0; m < 2; ++m)
#pragma unroll
            for (int n = 0; n < 2; ++n) {
                const int col = c0 + n*16 + al;
                const float bv = bias[col];
#pragma unroll
                for (int r = 0; r < 4; ++r) {
                    const int row = r0 + m*16 + ah*4 + r;
                    const float v = acc[m][n][r] + red[t][lane][(m*2 + n)*4 + r] + bv;
                    const size_t o = (size_t)row * N + col;
                    outF[o] = v + res[o];
                }
            }
    }
}

// ---------------------------------------------------------------------------
extern "C" void kernel_launch(void* const* d_in, const int* in_sizes, int n_in,
                              void* d_out, int out_size, void* d_ws, size_t ws_size,
                              hipStream_t stream)
{
    const float* x    = (const float*)d_in[0];
    const void*  mask = d_in[1];
    const float* ln1g = (const float*)d_in[2];
    const float* ln1b = (const float*)d_in[3];
    const float* ln2g = (const float*)d_in[4];
    const float* ln2b = (const float*)d_in[5];
    const float* Wq   = (const float*)d_in[6];
    const float* bq   = (const float*)d_in[7];
    const float* Wk   = (const float*)d_in[8];
    const float* bk   = (const float*)d_in[9];
    const float* Wv   = (const float*)d_in[10];
    const float* bv   = (const float*)d_in[11];
    const float* Wo   = (const float*)d_in[12];
    const float* bo   = (const float*)d_in[13];
    const float* W1   = (const float*)d_in[14];
    const float* b1   = (const float*)d_in[15];
    const float* W2   = (const float*)d_in[16];
    const float* b2   = (const float*)d_in[17];

    // Workspace (~42.2 MB), NO aliasing.
    char* w = (char*)d_ws;
    unsigned* flag        = (unsigned*)(w);                        // 4 B
    __hip_bfloat16* qh    = (__hip_bfloat16*)(w + 4096);           // 2 MB
    __hip_bfloat16* kh    = qh  + (size_t)MROWS * HID;             // 2 MB
    __hip_bfloat16* vt    = kh  + (size_t)MROWS * HID;             // 2 MB
    __hip_bfloat16* nx    = vt  + (size_t)MROWS * HID;             // 2 MB
    __hip_bfloat16* attn_b= nx  + (size_t)MROWS * HID;             // 2 MB
    __hip_bfloat16* nx2   = attn_b + (size_t)MROWS * HID;          // 2 MB
    __hip_bfloat16* hbuf  = nx2 + (size_t)MROWS * HID;             // 8 MB
    float* x1             = (float*)(hbuf + (size_t)MROWS * 4*HID);// 4 MB
    __hip_bfloat16* Wtqkv = (__hip_bfloat16*)(x1 + (size_t)MROWS * HID);
    __hip_bfloat16* Wto   = Wtqkv + 196608;                        // [256][256]
    __hip_bfloat16* Wt1   = Wto + 65536;                           // [1024][256]
    __hip_bfloat16* Wt2   = Wt1 + 262144;                          // [256][1024]
    float* part_o         = (float*)(Wt2 + 262144);                // 16 MB
    float* part_l         = part_o + (size_t)8192 * 512;           // 512 KB
    float* ob   = (float*)d_out;

    hipMemsetAsync(flag, 0, 4, stream);
    detect_mask<<<128, 256, 0, stream>>>((const unsigned*)mask, flag);
    tconv_all<<<768, 256, 0, stream>>>(Wq, Wk, Wv, Wo, W1, W2, Wtqkv, Wto, Wt1, Wt2);
    ln_wave<<<MROWS/4, 256, 0, stream>>>(x, ln1g, ln1b, nx);
    gemm_qkv<<<dim3(64,12), 256, 0, stream>>>(nx, Wtqkv, bq, bk, bv, qh, kh, vt);
    attn_part<<<2048, 256, 0, stream>>>(qh, kh, vt, mask, flag, part_o, part_l);
    attn_comb<<<4096, 256, 0, stream>>>(part_o, part_l, attn_b);
    gemm_ks<256><<<dim3(64,4), 512, 0, stream>>>(attn_b, Wto, bo, x, x1, HID);
    ln_wave<<<MROWS/4, 256, 0, stream>>>(x1, ln2g, ln2b, nx2);
    gemm_mfma<256,2><<<dim3(64,16), 256, 0, stream>>>(nx2, Wt1, b1, nullptr, nullptr, hbuf, 4*HID);
    gemm_ks<1024><<<dim3(64,4), 512, 0, stream>>>(hbuf, Wt2, b2, x1, ob, HID);
}

// Round 12
// 241.521 us; speedup vs baseline: 1.1170x; 1.0743x over previous
//
#include <hip/hip_runtime.h>
#include <hip/hip_bf16.h>

#define HID 256
#define HEADS 8
#define HDIM 32
#define BATCH 2
#define SEQ 2048
#define MROWS (BATCH*SEQ)   // 4096
#define SCALE 0.17677669529663687f

typedef __attribute__((ext_vector_type(8))) short short8;   // 8 bf16 (4 VGPRs)
typedef __attribute__((ext_vector_type(4))) float f32x4;
typedef __attribute__((ext_vector_type(4))) unsigned uint4v;

static __device__ __forceinline__ unsigned short f2bf(float x) {
    __hip_bfloat16 h = __float2bfloat16(x);
    return __builtin_bit_cast(unsigned short, h);
}
static __device__ __forceinline__ unsigned cvtpk(float lo, float hi) {
    unsigned r;
    asm("v_cvt_pk_bf16_f32 %0, %1, %2" : "=v"(r) : "v"(lo), "v"(hi));
    return r;
}

// ---------------------------------------------------------------------------
// Mask dtype detection: scan first 1MB as u32 words. flag!=0 => byte mask.
// ---------------------------------------------------------------------------
__global__ __launch_bounds__(256) void detect_mask(const unsigned* __restrict__ m,
                                                   unsigned* __restrict__ flag)
{
    unsigned bad = 0;
    for (size_t i = (size_t)blockIdx.x * 256 + threadIdx.x; i < 262144u;
         i += (size_t)gridDim.x * 256) {
        const unsigned wv = m[i];
        if (wv != 0u && wv != 1u && wv != 0x3F800000u) bad = 1;
    }
    if (__ballot(bad)) {
        if ((threadIdx.x & 63) == 0) atomicOr(flag, 1u);
    }
}

// ---------------------------------------------------------------------------
// Pack mask to 1 bit/entry: bm[row][2048 bits]; bit (k&31) of u32 word k>>5.
// One block per row; thread t packs keys 8t..8t+8 into byte t.
// ---------------------------------------------------------------------------
__global__ __launch_bounds__(256) void pack_mask(const void* __restrict__ mask,
                                                 const unsigned* __restrict__ flag,
                                                 unsigned char* __restrict__ bm)
{
    const int row = blockIdx.x, t = threadIdx.x;
    unsigned byte = 0;
    if (*flag != 0) {
        const unsigned char* src = (const unsigned char*)mask + ((size_t)row << 11) + t*8;
#pragma unroll
        for (int i = 0; i < 8; ++i) byte |= (unsigned)(src[i] != 0) << i;
    } else {
        const unsigned* src = (const unsigned*)mask + ((size_t)row << 11) + t*8;
#pragma unroll
        for (int i = 0; i < 8; ++i) byte |= (unsigned)(src[i] != 0u) << i;
    }
    bm[((size_t)row << 8) + t] = (unsigned char)byte;
}

// ---------------------------------------------------------------------------
// All weight transposes in ONE launch: W[K][N] fp32 -> Wt[N][K] bf16.
// ---------------------------------------------------------------------------
__global__ __launch_bounds__(256) void tconv_all(
    const float* __restrict__ Wq, const float* __restrict__ Wk,
    const float* __restrict__ Wv, const float* __restrict__ Wo,
    const float* __restrict__ W1, const float* __restrict__ W2,
    __hip_bfloat16* __restrict__ Wtqkv, __hip_bfloat16* __restrict__ Wto,
    __hip_bfloat16* __restrict__ Wt1,   __hip_bfloat16* __restrict__ Wt2)
{
    const int t = blockIdx.x;
    const float* W; __hip_bfloat16* Wt; int K, N, tt;
    if      (t < 64)  { W = Wq; Wt = Wtqkv;          K = 256;  N = 256;  tt = t; }
    else if (t < 128) { W = Wk; Wt = Wtqkv + 65536;  K = 256;  N = 256;  tt = t - 64; }
    else if (t < 192) { W = Wv; Wt = Wtqkv + 131072; K = 256;  N = 256;  tt = t - 128; }
    else if (t < 256) { W = Wo; Wt = Wto;            K = 256;  N = 256;  tt = t - 192; }
    else if (t < 512) { W = W1; Wt = Wt1;            K = 256;  N = 1024; tt = t - 256; }
    else              { W = W2; Wt = Wt2;            K = 1024; N = 256;  tt = t - 512; }
    const int nt = N >> 5;
    const int n0 = (tt % nt) * 32, k0 = (tt / nt) * 32;
    __shared__ float tle[32][33];
    const int tx = threadIdx.x & 31, ty = threadIdx.x >> 5;
#pragma unroll
    for (int i = 0; i < 4; ++i)
        tle[ty + i*8][tx] = W[(size_t)(k0 + ty + i*8) * N + n0 + tx];
    __syncthreads();
#pragma unroll
    for (int i = 0; i < 4; ++i)
        Wt[(size_t)(n0 + ty + i*8) * K + k0 + tx] = __float2bfloat16(tle[tx][ty + i*8]);
}

// ---------------------------------------------------------------------------
// LayerNorm, wave-per-row: 4 rows/block, float4 loads, shfl reductions.
// ---------------------------------------------------------------------------
__global__ __launch_bounds__(256) void ln_wave(const float* __restrict__ in,
                                               const float* __restrict__ g,
                                               const float* __restrict__ b,
                                               __hip_bfloat16* __restrict__ out)
{
    const int wave = threadIdx.x >> 6, lane = threadIdx.x & 63;
    const int row = blockIdx.x * 4 + wave;
    const float4 v = ((const float4*)(in + ((size_t)row << 8)))[lane];
    float s = v.x + v.y + v.z + v.w;
    for (int o = 32; o; o >>= 1) s += __shfl_xor(s, o);
    const float m = s * (1.f/HID);
    const float4 dv = make_float4(v.x - m, v.y - m, v.z - m, v.w - m);
    float vs = dv.x*dv.x + dv.y*dv.y + dv.z*dv.z + dv.w*dv.w;
    for (int o = 32; o; o >>= 1) vs += __shfl_xor(vs, o);
    const float rstd = rsqrtf(vs * (1.f/HID) + 1e-5f);
    const float4 gv = ((const float4*)g)[lane];
    const float4 bv = ((const float4*)b)[lane];
    ushort4 o4;
    o4.x = f2bf(dv.x * rstd * gv.x + bv.x);
    o4.y = f2bf(dv.y * rstd * gv.y + bv.y);
    o4.z = f2bf(dv.z * rstd * gv.z + bv.z);
    o4.w = f2bf(dv.w * rstd * gv.w + bv.w);
    ((ushort4*)(out + ((size_t)row << 8)))[lane] = o4;
}

// ---------------------------------------------------------------------------
// Fused QKV MFMA GEMM -> bf16 attention operands:
//   Q (b,h,s,d) bf16 PRE-SCALED by 1/sqrt(D);  K (b,h,s,d);  Vt (b,h,d,s).
// ---------------------------------------------------------------------------
__global__ __launch_bounds__(256) void gemm_qkv(const __hip_bfloat16* __restrict__ A,
                                                const __hip_bfloat16* __restrict__ Wt,
                                                const float* __restrict__ bq,
                                                const float* __restrict__ bk,
                                                const float* __restrict__ bv,
                                                __hip_bfloat16* __restrict__ qh,
                                                __hip_bfloat16* __restrict__ kh,
                                                __hip_bfloat16* __restrict__ vt)
{
    const int tid = threadIdx.x;
    const int wv = tid >> 6, lane = tid & 63;
    const int wr = wv >> 1, wc = wv & 1;
    const int r0 = blockIdx.x * 64 + wr * 32;
    const int c0 = blockIdx.y * 64 + wc * 32;
    const int al = lane & 15, ah = lane >> 4;

    f32x4 acc[2][2] = {};
    const short8* Ap[2];
    const short8* Bp[2];
#pragma unroll
    for (int m = 0; m < 2; ++m)
        Ap[m] = (const short8*)(A + (size_t)(r0 + m*16 + al) * 256 + ah * 8);
#pragma unroll
    for (int n = 0; n < 2; ++n)
        Bp[n] = (const short8*)(Wt + (size_t)(c0 + n*16 + al) * 256 + ah * 8);

#pragma unroll 8
    for (int kt = 0; kt < 8; ++kt) {
        short8 af[2], bf[2];
#pragma unroll
        for (int m = 0; m < 2; ++m) af[m] = Ap[m][kt*4];
#pragma unroll
        for (int n = 0; n < 2; ++n) bf[n] = Bp[n][kt*4];
#pragma unroll
        for (int m = 0; m < 2; ++m)
#pragma unroll
            for (int n = 0; n < 2; ++n)
                acc[m][n] = __builtin_amdgcn_mfma_f32_16x16x32_bf16(
                    af[m], bf[n], acc[m][n], 0, 0, 0);
    }

#pragma unroll
    for (int m = 0; m < 2; ++m)
#pragma unroll
        for (int n = 0; n < 2; ++n) {
            const int col = c0 + n*16 + al;
            const int which = col >> 8, cc = col & 255;
            const int h = cc >> 5, d = cc & 31;
            const float* bp = which == 0 ? bq : (which == 1 ? bk : bv);
            const float bvv = bp[cc];
            const int row0 = r0 + m*16 + ah*4;
            const int bb = row0 >> 11, s0 = row0 & 2047;
            if (which == 2) {
                ushort4 o4;
                o4.x = f2bf(acc[m][n][0] + bvv);
                o4.y = f2bf(acc[m][n][1] + bvv);
                o4.z = f2bf(acc[m][n][2] + bvv);
                o4.w = f2bf(acc[m][n][3] + bvv);
                *(ushort4*)(vt + ((size_t)((bb*8 + h)*32 + d) << 11) + s0) = o4;
            } else {
                __hip_bfloat16* op = which == 0 ? qh : kh;
                const float sc = which == 0 ? SCALE : 1.f;
#pragma unroll
                for (int r = 0; r < 4; ++r) {
                    const float v = (acc[m][n][r] + bvv) * sc;
                    op[(((size_t)(bb*8 + h) << 11) + s0 + r) * 32 + d] =
                        __float2bfloat16(v);
                }
            }
        }
}

// ---------------------------------------------------------------------------
// Dense masked flash attention, k-split x2, 1-bit mask. Wave wid:
// tile = wid>>1 (b,h,16-q tile), ks = wid&1 -> keys [ks*1024, +1024).
// Per iter: ONE u32 mask-word load per lane (bit (k&31) <-> key k).
// ---------------------------------------------------------------------------
__global__ __launch_bounds__(256) void attn_part(const __hip_bfloat16* __restrict__ Qh,
                                                 const __hip_bfloat16* __restrict__ Kh,
                                                 const __hip_bfloat16* __restrict__ Vt,
                                                 const unsigned* __restrict__ bm32,
                                                 float* __restrict__ part_o,
                                                 float* __restrict__ part_l)
{
    const int wave = threadIdx.x >> 6, lane = threadIdx.x & 63;
    const int wid = blockIdx.x * 4 + wave;       // 4096 waves
    const int tile = wid >> 1, ks = wid & 1;
    const int bh = tile >> 7, qt = tile & 127;
    const int b = bh >> 3;
    const int q0 = qt << 4;
    const int qi = lane & 15, g = lane >> 4;
    const int kbeg = ks << 10;

    const short8 qf = *(const short8*)(Qh + (((size_t)bh << 11) + q0 + qi) * 32 + g*8);

    const __hip_bfloat16* Kb = Kh + ((size_t)bh << 16);
    const __hip_bfloat16* Vb = Vt + ((size_t)bh << 16);
    const unsigned* mrow = bm32 + (((size_t)(b << 11) + q0 + qi) << 6); // 64 u32/row

    const int slA = ((2*g) & 3) * 16 + qi;       // src lane for B-frag w0,w1
    const int slB = ((2*g + 1) & 3) * 16 + qi;   // src lane for w2,w3
    const bool hi = g >= 2;

    f32x4 o0 = {}, o1 = {};
    const f32x4 zero = {};
    float lsum = 0.f;

    for (int k0 = kbeg; k0 < kbeg + 1024; k0 += 32) {
        const unsigned mwrd = mrow[k0 >> 5];
        const short8 kf0 = *(const short8*)(Kb + ((size_t)(k0      + qi) << 5) + g*8);
        const short8 kf1 = *(const short8*)(Kb + ((size_t)(k0 + 16 + qi) << 5) + g*8);
        const short8 vf0 = *(const short8*)(Vb + ((size_t) qi       << 11) + k0 + g*8);
        const short8 vf1 = *(const short8*)(Vb + ((size_t)(qi + 16) << 11) + k0 + g*8);

        f32x4 s0 = __builtin_amdgcn_mfma_f32_16x16x32_bf16(kf0, qf, zero, 0, 0, 0);
        f32x4 s1 = __builtin_amdgcn_mfma_f32_16x16x32_bf16(kf1, qf, zero, 0, 0, 0);

        float p0[4], p1[4];
#pragma unroll
        for (int r = 0; r < 4; ++r) {
            p0[r] = ((mwrd >> (     4*g + r)) & 1u) ? __expf(s0[r]) : 0.f;
            p1[r] = ((mwrd >> (16 + 4*g + r)) & 1u) ? __expf(s1[r]) : 0.f;
        }
        lsum += ((p0[0] + p0[1]) + (p0[2] + p0[3]))
              + ((p1[0] + p1[1]) + (p1[2] + p1[3]));

        const unsigned f0w0 = cvtpk(p0[0], p0[1]), f0w1 = cvtpk(p0[2], p0[3]);
        const unsigned f1w0 = cvtpk(p1[0], p1[1]), f1w1 = cvtpk(p1[2], p1[3]);

        const unsigned aw0 = __shfl(f0w0, slA), aw1 = __shfl(f0w1, slA);
        const unsigned aw2 = __shfl(f0w0, slB), aw3 = __shfl(f0w1, slB);
        const unsigned cw0 = __shfl(f1w0, slA), cw1 = __shfl(f1w1, slA);
        const unsigned cw2 = __shfl(f1w0, slB), cw3 = __shfl(f1w1, slB);
        uint4v pw;
        pw[0] = hi ? cw0 : aw0;
        pw[1] = hi ? cw1 : aw1;
        pw[2] = hi ? cw2 : aw2;
        pw[3] = hi ? cw3 : aw3;
        const short8 pb = __builtin_bit_cast(short8, pw);

        o0 = __builtin_amdgcn_mfma_f32_16x16x32_bf16(vf0, pb, o0, 0, 0, 0);
        o1 = __builtin_amdgcn_mfma_f32_16x16x32_bf16(vf1, pb, o1, 0, 0, 0);
    }

    lsum += __shfl_xor(lsum, 16);
    lsum += __shfl_xor(lsum, 32);

    float* po = part_o + ((size_t)wid << 9) + qi*32 + 4*g;
    *(f32x4*)(po)      = o0;
    *(f32x4*)(po + 16) = o1;
    if (g == 0) part_l[(wid << 4) + qi] = lsum;
}

// ---------------------------------------------------------------------------
// Merge 2 k-slices, normalize, emit bf16 attn (b, q, h*32+d) rows.
// ---------------------------------------------------------------------------
__global__ __launch_bounds__(256) void attn_comb(const float* __restrict__ part_o,
                                                 const float* __restrict__ part_l,
                                                 __hip_bfloat16* __restrict__ out)
{
    const int e = blockIdx.x * 256 + threadIdx.x;   // 2048 tiles x 512
    const int tile = e >> 9, j = e & 511;
    const int q = j >> 5, d = j & 31;
    const float a = part_o[((size_t)(tile*2) << 9) + j]
                  + part_o[((size_t)(tile*2+1) << 9) + j];
    const float l = part_l[((tile*2) << 4) + q] + part_l[((tile*2+1) << 4) + q];
    const int bh = tile >> 7, qt = tile & 127;
    const int b = bh >> 3, h = bh & 7;
    out[(((size_t)b << 11) + qt*16 + q) * 256 + h*32 + d] = __float2bfloat16(a / l);
}

// ---------------------------------------------------------------------------
// bf16 MFMA GEMM, 4 waves, 64x64 block, 32x32 wave tile.
// EPI 2: GELU -> bf16 (W1).  EPI 1: +res -> fp32.
// ---------------------------------------------------------------------------
template<int KTOT, int EPI>
__global__ __launch_bounds__(256) void gemm_mfma(const __hip_bfloat16* __restrict__ A,
                                                 const __hip_bfloat16* __restrict__ Wt,
                                                 const float* __restrict__ bias,
                                                 const float* __restrict__ res,
                                                 float* __restrict__ outF,
                                                 __hip_bfloat16* __restrict__ outB,
                                                 int N)
{
    const int tid = threadIdx.x;
    const int wv = tid >> 6, lane = tid & 63;
    const int wr = wv >> 1, wc = wv & 1;
    const int r0 = blockIdx.x * 64 + wr * 32;
    const int c0 = blockIdx.y * 64 + wc * 32;
    const int al = lane & 15, ah = lane >> 4;

    f32x4 acc[2][2] = {};
    const short8* Ap[2];
    const short8* Bp[2];
#pragma unroll
    for (int m = 0; m < 2; ++m)
        Ap[m] = (const short8*)(A + (size_t)(r0 + m*16 + al) * KTOT + ah * 8);
#pragma unroll
    for (int n = 0; n < 2; ++n)
        Bp[n] = (const short8*)(Wt + (size_t)(c0 + n*16 + al) * KTOT + ah * 8);

#pragma unroll 8
    for (int kt = 0; kt < KTOT/32; ++kt) {
        short8 af[2], bf[2];
#pragma unroll
        for (int m = 0; m < 2; ++m) af[m] = Ap[m][kt*4];
#pragma unroll
        for (int n = 0; n < 2; ++n) bf[n] = Bp[n][kt*4];
#pragma unroll
        for (int m = 0; m < 2; ++m)
#pragma unroll
            for (int n = 0; n < 2; ++n)
                acc[m][n] = __builtin_amdgcn_mfma_f32_16x16x32_bf16(
                    af[m], bf[n], acc[m][n], 0, 0, 0);
    }

#pragma unroll
    for (int m = 0; m < 2; ++m)
#pragma unroll
        for (int n = 0; n < 2; ++n) {
            const int col = c0 + n*16 + al;
            const float bv = bias[col];
#pragma unroll
            for (int r = 0; r < 4; ++r) {
                const int row = r0 + m*16 + ah*4 + r;
                const float v = acc[m][n][r] + bv;
                const size_t o = (size_t)row * N + col;
                if (EPI == 1) {
                    outF[o] = v + res[o];
                } else {
                    outB[o] = __float2bfloat16(
                        0.5f * v * (1.0f + erff(v * 0.70710678118654752f)));
                }
            }
        }
}

// ---------------------------------------------------------------------------
// K-split GEMM for N=256 outputs (Wo, W2): 512 threads = 8 waves =
// 4 output tiles (32x32) x 2 K-halves; f32 LDS combine; +res epilogue.
// ---------------------------------------------------------------------------
template<int KTOT>
__global__ __launch_bounds__(512) void gemm_ks(const __hip_bfloat16* __restrict__ A,
                                               const __hip_bfloat16* __restrict__ Wt,
                                               const float* __restrict__ bias,
                                               const float* __restrict__ res,
                                               float* __restrict__ outF,
                                               int N)
{
    constexpr int KH = KTOT / 2;
    __shared__ float red[4][64][17];
    const int tid = threadIdx.x;
    const int wv = tid >> 6, lane = tid & 63;
    const int t = wv & 3, ks = wv >> 2;
    const int wr = t >> 1, wc = t & 1;
    const int r0 = blockIdx.x * 64 + wr * 32;
    const int c0 = blockIdx.y * 64 + wc * 32;
    const int al = lane & 15, ah = lane >> 4;

    f32x4 acc[2][2] = {};
    const short8* Ap[2];
    const short8* Bp[2];
#pragma unroll
    for (int m = 0; m < 2; ++m)
        Ap[m] = (const short8*)(A + (size_t)(r0 + m*16 + al) * KTOT + ks*KH + ah * 8);
#pragma unroll
    for (int n = 0; n < 2; ++n)
        Bp[n] = (const short8*)(Wt + (size_t)(c0 + n*16 + al) * KTOT + ks*KH + ah * 8);

#pragma unroll 8
    for (int kt = 0; kt < KH/32; ++kt) {
        short8 af[2], bf[2];
#pragma unroll
        for (int m = 0; m < 2; ++m) af[m] = Ap[m][kt*4];
#pragma unroll
        for (int n = 0; n < 2; ++n) bf[n] = Bp[n][kt*4];
#pragma unroll
        for (int m = 0; m < 2; ++m)
#pragma unroll
            for (int n = 0; n < 2; ++n)
                acc[m][n] = __builtin_amdgcn_mfma_f32_16x16x32_bf16(
                    af[m], bf[n], acc[m][n], 0, 0, 0);
    }

    if (ks == 1) {
#pragma unroll
        for (int m = 0; m < 2; ++m)
#pragma unroll
            for (int n = 0; n < 2; ++n)
#pragma unroll
                for (int r = 0; r < 4; ++r)
                    red[t][lane][(m*2 + n)*4 + r] = acc[m][n][r];
    }
    __syncthreads();
    if (ks == 0) {
#pragma unroll
        for (int m = 0; m < 2; ++m)
#pragma unroll
            for (int n = 0; n < 2; ++n) {
                const int col = c0 + n*16 + al;
                const float bv = bias[col];
#pragma unroll
                for (int r = 0; r < 4; ++r) {
                    const int row = r0 + m*16 + ah*4 + r;
                    const float v = acc[m][n][r] + red[t][lane][(m*2 + n)*4 + r] + bv;
                    const size_t o = (size_t)row * N + col;
                    outF[o] = v + res[o];
                }
            }
    }
}

// ---------------------------------------------------------------------------
extern "C" void kernel_launch(void* const* d_in, const int* in_sizes, int n_in,
                              void* d_out, int out_size, void* d_ws, size_t ws_size,
                              hipStream_t stream)
{
    const float* x    = (const float*)d_in[0];
    const void*  mask = d_in[1];
    const float* ln1g = (const float*)d_in[2];
    const float* ln1b = (const float*)d_in[3];
    const float* ln2g = (const float*)d_in[4];
    const float* ln2b = (const float*)d_in[5];
    const float* Wq   = (const float*)d_in[6];
    const float* bq   = (const float*)d_in[7];
    const float* Wk   = (const float*)d_in[8];
    const float* bk   = (const float*)d_in[9];
    const float* Wv   = (const float*)d_in[10];
    const float* bv   = (const float*)d_in[11];
    const float* Wo   = (const float*)d_in[12];
    const float* bo   = (const float*)d_in[13];
    const float* W1   = (const float*)d_in[14];
    const float* b1   = (const float*)d_in[15];
    const float* W2   = (const float*)d_in[16];
    const float* b2   = (const float*)d_in[17];

    // Workspace (~35 MB), NO aliasing.
    char* w = (char*)d_ws;
    unsigned* flag        = (unsigned*)(w);                        // 4 B
    unsigned char* bmask  = (unsigned char*)(w + 4096);            // 1 MB
    __hip_bfloat16* qh    = (__hip_bfloat16*)(w + 4096 + (1 << 20));  // 2 MB
    __hip_bfloat16* kh    = qh  + (size_t)MROWS * HID;             // 2 MB
    __hip_bfloat16* vt    = kh  + (size_t)MROWS * HID;             // 2 MB
    __hip_bfloat16* nx    = vt  + (size_t)MROWS * HID;             // 2 MB
    __hip_bfloat16* attn_b= nx  + (size_t)MROWS * HID;             // 2 MB
    __hip_bfloat16* nx2   = attn_b + (size_t)MROWS * HID;          // 2 MB
    __hip_bfloat16* hbuf  = nx2 + (size_t)MROWS * HID;             // 8 MB
    float* x1             = (float*)(hbuf + (size_t)MROWS * 4*HID);// 4 MB
    __hip_bfloat16* Wtqkv = (__hip_bfloat16*)(x1 + (size_t)MROWS * HID);
    __hip_bfloat16* Wto   = Wtqkv + 196608;                        // [256][256]
    __hip_bfloat16* Wt1   = Wto + 65536;                           // [1024][256]
    __hip_bfloat16* Wt2   = Wt1 + 262144;                          // [256][1024]
    float* part_o         = (float*)(Wt2 + 262144);                // 8 MB
    float* part_l         = part_o + (size_t)4096 * 512;           // 256 KB
    float* ob   = (float*)d_out;

    hipMemsetAsync(flag, 0, 4, stream);
    detect_mask<<<128, 256, 0, stream>>>((const unsigned*)mask, flag);
    pack_mask<<<MROWS, 256, 0, stream>>>(mask, flag, bmask);
    tconv_all<<<768, 256, 0, stream>>>(Wq, Wk, Wv, Wo, W1, W2, Wtqkv, Wto, Wt1, Wt2);
    ln_wave<<<MROWS/4, 256, 0, stream>>>(x, ln1g, ln1b, nx);
    gemm_qkv<<<dim3(64,12), 256, 0, stream>>>(nx, Wtqkv, bq, bk, bv, qh, kh, vt);
    attn_part<<<1024, 256, 0, stream>>>(qh, kh, vt, (const unsigned*)bmask,
                                        part_o, part_l);
    attn_comb<<<4096, 256, 0, stream>>>(part_o, part_l, attn_b);
    gemm_ks<256><<<dim3(64,4), 512, 0, stream>>>(attn_b, Wto, bo, x, x1, HID);
    ln_wave<<<MROWS/4, 256, 0, stream>>>(x1, ln2g, ln2b, nx2);
    gemm_mfma<256,2><<<dim3(64,16), 256, 0, stream>>>(nx2, Wt1, b1, nullptr, nullptr, hbuf, 4*HID);
    gemm_ks<1024><<<dim3(64,4), 512, 0, stream>>>(hbuf, Wt2, b2, x1, ob, HID);
}

// Round 13
// 237.543 us; speedup vs baseline: 1.1357x; 1.0167x over previous
//
#include <hip/hip_runtime.h>
#include <hip/hip_bf16.h>

#define HID 256
#define HEADS 8
#define HDIM 32
#define BATCH 2
#define SEQ 2048
#define MROWS (BATCH*SEQ)   // 4096
#define SCALE 0.17677669529663687f

typedef __attribute__((ext_vector_type(8))) short short8;   // 8 bf16 (4 VGPRs)
typedef __attribute__((ext_vector_type(4))) float f32x4;
typedef __attribute__((ext_vector_type(4))) unsigned uint4v;

static __device__ __forceinline__ unsigned short f2bf(float x) {
    __hip_bfloat16 h = __float2bfloat16(x);
    return __builtin_bit_cast(unsigned short, h);
}
static __device__ __forceinline__ unsigned cvtpk(float lo, float hi) {
    unsigned r;
    asm("v_cvt_pk_bf16_f32 %0, %1, %2" : "=v"(r) : "v"(lo), "v"(hi));
    return r;
}

// ---------------------------------------------------------------------------
// Pack mask to 1 bit/entry with built-in dtype detection. Every block scans
// the buffer's FIRST 512 words (in-bounds under both layouts): int32/fp32
// masks only contain {0,1,0x3F800000}; a byte mask at 5% density violates
// w.p. 1 - e^-79. Then thread t packs keys 8t..8t+7 of row blockIdx.x into
// byte t of bm[row][256].
// ---------------------------------------------------------------------------
__global__ __launch_bounds__(256) void pack_mask(const void* __restrict__ mask,
                                                 unsigned char* __restrict__ bm)
{
    __shared__ int bmflag;
    const int row = blockIdx.x, t = threadIdx.x;
    if (t == 0) bmflag = 0;
    __syncthreads();
    {
        const unsigned* w0 = (const unsigned*)mask;
        const unsigned a = w0[t], b = w0[t + 256];
        int bad = (a != 0u && a != 1u && a != 0x3F800000u) ||
                  (b != 0u && b != 1u && b != 0x3F800000u);
        if (bad) atomicOr(&bmflag, 1);
    }
    __syncthreads();
    unsigned byte = 0;
    if (bmflag) {
        const unsigned char* src = (const unsigned char*)mask + ((size_t)row << 11) + t*8;
#pragma unroll
        for (int i = 0; i < 8; ++i) byte |= (unsigned)(src[i] != 0) << i;
    } else {
        const unsigned* src = (const unsigned*)mask + ((size_t)row << 11) + t*8;
#pragma unroll
        for (int i = 0; i < 8; ++i) byte |= (unsigned)(src[i] != 0u) << i;
    }
    bm[((size_t)row << 8) + t] = (unsigned char)byte;
}

// ---------------------------------------------------------------------------
// All weight transposes in ONE launch: W[K][N] fp32 -> Wt[N][K] bf16.
// ---------------------------------------------------------------------------
__global__ __launch_bounds__(256) void tconv_all(
    const float* __restrict__ Wq, const float* __restrict__ Wk,
    const float* __restrict__ Wv, const float* __restrict__ Wo,
    const float* __restrict__ W1, const float* __restrict__ W2,
    __hip_bfloat16* __restrict__ Wtqkv, __hip_bfloat16* __restrict__ Wto,
    __hip_bfloat16* __restrict__ Wt1,   __hip_bfloat16* __restrict__ Wt2)
{
    const int t = blockIdx.x;
    const float* W; __hip_bfloat16* Wt; int K, N, tt;
    if      (t < 64)  { W = Wq; Wt = Wtqkv;          K = 256;  N = 256;  tt = t; }
    else if (t < 128) { W = Wk; Wt = Wtqkv + 65536;  K = 256;  N = 256;  tt = t - 64; }
    else if (t < 192) { W = Wv; Wt = Wtqkv + 131072; K = 256;  N = 256;  tt = t - 128; }
    else if (t < 256) { W = Wo; Wt = Wto;            K = 256;  N = 256;  tt = t - 192; }
    else if (t < 512) { W = W1; Wt = Wt1;            K = 256;  N = 1024; tt = t - 256; }
    else              { W = W2; Wt = Wt2;            K = 1024; N = 256;  tt = t - 512; }
    const int nt = N >> 5;
    const int n0 = (tt % nt) * 32, k0 = (tt / nt) * 32;
    __shared__ float tle[32][33];
    const int tx = threadIdx.x & 31, ty = threadIdx.x >> 5;
#pragma unroll
    for (int i = 0; i < 4; ++i)
        tle[ty + i*8][tx] = W[(size_t)(k0 + ty + i*8) * N + n0 + tx];
    __syncthreads();
#pragma unroll
    for (int i = 0; i < 4; ++i)
        Wt[(size_t)(n0 + ty + i*8) * K + k0 + tx] = __float2bfloat16(tle[tx][ty + i*8]);
}

// ---------------------------------------------------------------------------
// LayerNorm, wave-per-row: 4 rows/block, float4 loads, shfl reductions.
// ---------------------------------------------------------------------------
__global__ __launch_bounds__(256) void ln_wave(const float* __restrict__ in,
                                               const float* __restrict__ g,
                                               const float* __restrict__ b,
                                               __hip_bfloat16* __restrict__ out)
{
    const int wave = threadIdx.x >> 6, lane = threadIdx.x & 63;
    const int row = blockIdx.x * 4 + wave;
    const float4 v = ((const float4*)(in + ((size_t)row << 8)))[lane];
    float s = v.x + v.y + v.z + v.w;
    for (int o = 32; o; o >>= 1) s += __shfl_xor(s, o);
    const float m = s * (1.f/HID);
    const float4 dv = make_float4(v.x - m, v.y - m, v.z - m, v.w - m);
    float vs = dv.x*dv.x + dv.y*dv.y + dv.z*dv.z + dv.w*dv.w;
    for (int o = 32; o; o >>= 1) vs += __shfl_xor(vs, o);
    const float rstd = rsqrtf(vs * (1.f/HID) + 1e-5f);
    const float4 gv = ((const float4*)g)[lane];
    const float4 bv = ((const float4*)b)[lane];
    ushort4 o4;
    o4.x = f2bf(dv.x * rstd * gv.x + bv.x);
    o4.y = f2bf(dv.y * rstd * gv.y + bv.y);
    o4.z = f2bf(dv.z * rstd * gv.z + bv.z);
    o4.w = f2bf(dv.w * rstd * gv.w + bv.w);
    ((ushort4*)(out + ((size_t)row << 8)))[lane] = o4;
}

// ---------------------------------------------------------------------------
// Fused QKV MFMA GEMM -> bf16 attention operands:
//   Q (b,h,s,d) bf16 PRE-SCALED by 1/sqrt(D);  K (b,h,s,d);  Vt (b,h,d,s).
// ---------------------------------------------------------------------------
__global__ __launch_bounds__(256) void gemm_qkv(const __hip_bfloat16* __restrict__ A,
                                                const __hip_bfloat16* __restrict__ Wt,
                                                const float* __restrict__ bq,
                                                const float* __restrict__ bk,
                                                const float* __restrict__ bv,
                                                __hip_bfloat16* __restrict__ qh,
                                                __hip_bfloat16* __restrict__ kh,
                                                __hip_bfloat16* __restrict__ vt)
{
    const int tid = threadIdx.x;
    const int wv = tid >> 6, lane = tid & 63;
    const int wr = wv >> 1, wc = wv & 1;
    const int r0 = blockIdx.x * 64 + wr * 32;
    const int c0 = blockIdx.y * 64 + wc * 32;
    const int al = lane & 15, ah = lane >> 4;

    f32x4 acc[2][2] = {};
    const short8* Ap[2];
    const short8* Bp[2];
#pragma unroll
    for (int m = 0; m < 2; ++m)
        Ap[m] = (const short8*)(A + (size_t)(r0 + m*16 + al) * 256 + ah * 8);
#pragma unroll
    for (int n = 0; n < 2; ++n)
        Bp[n] = (const short8*)(Wt + (size_t)(c0 + n*16 + al) * 256 + ah * 8);

#pragma unroll 8
    for (int kt = 0; kt < 8; ++kt) {
        short8 af[2], bf[2];
#pragma unroll
        for (int m = 0; m < 2; ++m) af[m] = Ap[m][kt*4];
#pragma unroll
        for (int n = 0; n < 2; ++n) bf[n] = Bp[n][kt*4];
#pragma unroll
        for (int m = 0; m < 2; ++m)
#pragma unroll
            for (int n = 0; n < 2; ++n)
                acc[m][n] = __builtin_amdgcn_mfma_f32_16x16x32_bf16(
                    af[m], bf[n], acc[m][n], 0, 0, 0);
    }

#pragma unroll
    for (int m = 0; m < 2; ++m)
#pragma unroll
        for (int n = 0; n < 2; ++n) {
            const int col = c0 + n*16 + al;
            const int which = col >> 8, cc = col & 255;
            const int h = cc >> 5, d = cc & 31;
            const float* bp = which == 0 ? bq : (which == 1 ? bk : bv);
            const float bvv = bp[cc];
            const int row0 = r0 + m*16 + ah*4;
            const int bb = row0 >> 11, s0 = row0 & 2047;
            if (which == 2) {
                ushort4 o4;
                o4.x = f2bf(acc[m][n][0] + bvv);
                o4.y = f2bf(acc[m][n][1] + bvv);
                o4.z = f2bf(acc[m][n][2] + bvv);
                o4.w = f2bf(acc[m][n][3] + bvv);
                *(ushort4*)(vt + ((size_t)((bb*8 + h)*32 + d) << 11) + s0) = o4;
            } else {
                __hip_bfloat16* op = which == 0 ? qh : kh;
                const float sc = which == 0 ? SCALE : 1.f;
#pragma unroll
                for (int r = 0; r < 4; ++r) {
                    const float v = (acc[m][n][r] + bvv) * sc;
                    op[(((size_t)(bb*8 + h) << 11) + s0 + r) * 32 + d] =
                        __float2bfloat16(v);
                }
            }
        }
}

// ---------------------------------------------------------------------------
// Dense masked flash attention, k-split x4, 1-bit mask. Wave wid:
// tile = wid>>2 (b,h,16-q tile), ks = wid&3 -> keys [ks*512, +512).
// Per iter: ONE u32 mask-word load per lane (bit (k&31) <-> key k).
// ---------------------------------------------------------------------------
__global__ __launch_bounds__(256) void attn_part(const __hip_bfloat16* __restrict__ Qh,
                                                 const __hip_bfloat16* __restrict__ Kh,
                                                 const __hip_bfloat16* __restrict__ Vt,
                                                 const unsigned* __restrict__ bm32,
                                                 float* __restrict__ part_o,
                                                 float* __restrict__ part_l)
{
    const int wave = threadIdx.x >> 6, lane = threadIdx.x & 63;
    const int wid = blockIdx.x * 4 + wave;       // 8192 waves
    const int tile = wid >> 2, ks = wid & 3;
    const int bh = tile >> 7, qt = tile & 127;
    const int b = bh >> 3;
    const int q0 = qt << 4;
    const int qi = lane & 15, g = lane >> 4;
    const int kbeg = ks << 9;

    const short8 qf = *(const short8*)(Qh + (((size_t)bh << 11) + q0 + qi) * 32 + g*8);

    const __hip_bfloat16* Kb = Kh + ((size_t)bh << 16);
    const __hip_bfloat16* Vb = Vt + ((size_t)bh << 16);
    const unsigned* mrow = bm32 + (((size_t)(b << 11) + q0 + qi) << 6); // 64 u32/row

    const int slA = ((2*g) & 3) * 16 + qi;       // src lane for B-frag w0,w1
    const int slB = ((2*g + 1) & 3) * 16 + qi;   // src lane for w2,w3
    const bool hi = g >= 2;

    f32x4 o0 = {}, o1 = {};
    const f32x4 zero = {};
    float lsum = 0.f;

    for (int k0 = kbeg; k0 < kbeg + 512; k0 += 32) {
        const unsigned mwrd = mrow[k0 >> 5];
        const short8 kf0 = *(const short8*)(Kb + ((size_t)(k0      + qi) << 5) + g*8);
        const short8 kf1 = *(const short8*)(Kb + ((size_t)(k0 + 16 + qi) << 5) + g*8);
        const short8 vf0 = *(const short8*)(Vb + ((size_t) qi       << 11) + k0 + g*8);
        const short8 vf1 = *(const short8*)(Vb + ((size_t)(qi + 16) << 11) + k0 + g*8);

        f32x4 s0 = __builtin_amdgcn_mfma_f32_16x16x32_bf16(kf0, qf, zero, 0, 0, 0);
        f32x4 s1 = __builtin_amdgcn_mfma_f32_16x16x32_bf16(kf1, qf, zero, 0, 0, 0);

        float p0[4], p1[4];
#pragma unroll
        for (int r = 0; r < 4; ++r) {
            p0[r] = ((mwrd >> (     4*g + r)) & 1u) ? __expf(s0[r]) : 0.f;
            p1[r] = ((mwrd >> (16 + 4*g + r)) & 1u) ? __expf(s1[r]) : 0.f;
        }
        lsum += ((p0[0] + p0[1]) + (p0[2] + p0[3]))
              + ((p1[0] + p1[1]) + (p1[2] + p1[3]));

        const unsigned f0w0 = cvtpk(p0[0], p0[1]), f0w1 = cvtpk(p0[2], p0[3]);
        const unsigned f1w0 = cvtpk(p1[0], p1[1]), f1w1 = cvtpk(p1[2], p1[3]);

        const unsigned aw0 = __shfl(f0w0, slA), aw1 = __shfl(f0w1, slA);
        const unsigned aw2 = __shfl(f0w0, slB), aw3 = __shfl(f0w1, slB);
        const unsigned cw0 = __shfl(f1w0, slA), cw1 = __shfl(f1w1, slA);
        const unsigned cw2 = __shfl(f1w0, slB), cw3 = __shfl(f1w1, slB);
        uint4v pw;
        pw[0] = hi ? cw0 : aw0;
        pw[1] = hi ? cw1 : aw1;
        pw[2] = hi ? cw2 : aw2;
        pw[3] = hi ? cw3 : aw3;
        const short8 pb = __builtin_bit_cast(short8, pw);

        o0 = __builtin_amdgcn_mfma_f32_16x16x32_bf16(vf0, pb, o0, 0, 0, 0);
        o1 = __builtin_amdgcn_mfma_f32_16x16x32_bf16(vf1, pb, o1, 0, 0, 0);
    }

    lsum += __shfl_xor(lsum, 16);
    lsum += __shfl_xor(lsum, 32);

    float* po = part_o + ((size_t)wid << 9) + qi*32 + 4*g;
    *(f32x4*)(po)      = o0;
    *(f32x4*)(po + 16) = o1;
    if (g == 0) part_l[(wid << 4) + qi] = lsum;
}

// ---------------------------------------------------------------------------
// Merge 4 k-slices, normalize, emit bf16 attn (b, q, h*32+d) rows.
// ---------------------------------------------------------------------------
__global__ __launch_bounds__(256) void attn_comb(const float* __restrict__ part_o,
                                                 const float* __restrict__ part_l,
                                                 __hip_bfloat16* __restrict__ out)
{
    const int e = blockIdx.x * 256 + threadIdx.x;   // 2048 tiles x 512
    const int tile = e >> 9, j = e & 511;
    const int q = j >> 5, d = j & 31;
    float a = 0.f, l = 0.f;
#pragma unroll
    for (int s = 0; s < 4; ++s) {
        a += part_o[((size_t)(tile*4 + s) << 9) + j];
        l += part_l[((tile*4 + s) << 4) + q];
    }
    const int bh = tile >> 7, qt = tile & 127;
    const int b = bh >> 3, h = bh & 7;
    out[(((size_t)b << 11) + qt*16 + q) * 256 + h*32 + d] = __float2bfloat16(a / l);
}

// ---------------------------------------------------------------------------
// bf16 MFMA GEMM, 4 waves, 64x64 block, 32x32 wave tile.
// EPI 2: GELU -> bf16 (W1).  EPI 1: +res -> fp32.
// ---------------------------------------------------------------------------
template<int KTOT, int EPI>
__global__ __launch_bounds__(256) void gemm_mfma(const __hip_bfloat16* __restrict__ A,
                                                 const __hip_bfloat16* __restrict__ Wt,
                                                 const float* __restrict__ bias,
                                                 const float* __restrict__ res,
                                                 float* __restrict__ outF,
                                                 __hip_bfloat16* __restrict__ outB,
                                                 int N)
{
    const int tid = threadIdx.x;
    const int wv = tid >> 6, lane = tid & 63;
    const int wr = wv >> 1, wc = wv & 1;
    const int r0 = blockIdx.x * 64 + wr * 32;
    const int c0 = blockIdx.y * 64 + wc * 32;
    const int al = lane & 15, ah = lane >> 4;

    f32x4 acc[2][2] = {};
    const short8* Ap[2];
    const short8* Bp[2];
#pragma unroll
    for (int m = 0; m < 2; ++m)
        Ap[m] = (const short8*)(A + (size_t)(r0 + m*16 + al) * KTOT + ah * 8);
#pragma unroll
    for (int n = 0; n < 2; ++n)
        Bp[n] = (const short8*)(Wt + (size_t)(c0 + n*16 + al) * KTOT + ah * 8);

#pragma unroll 8
    for (int kt = 0; kt < KTOT/32; ++kt) {
        short8 af[2], bf[2];
#pragma unroll
        for (int m = 0; m < 2; ++m) af[m] = Ap[m][kt*4];
#pragma unroll
        for (int n = 0; n < 2; ++n) bf[n] = Bp[n][kt*4];
#pragma unroll
        for (int m = 0; m < 2; ++m)
#pragma unroll
            for (int n = 0; n < 2; ++n)
                acc[m][n] = __builtin_amdgcn_mfma_f32_16x16x32_bf16(
                    af[m], bf[n], acc[m][n], 0, 0, 0);
    }

#pragma unroll
    for (int m = 0; m < 2; ++m)
#pragma unroll
        for (int n = 0; n < 2; ++n) {
            const int col = c0 + n*16 + al;
            const float bv = bias[col];
#pragma unroll
            for (int r = 0; r < 4; ++r) {
                const int row = r0 + m*16 + ah*4 + r;
                const float v = acc[m][n][r] + bv;
                const size_t o = (size_t)row * N + col;
                if (EPI == 1) {
                    outF[o] = v + res[o];
                } else {
                    outB[o] = __float2bfloat16(
                        0.5f * v * (1.0f + erff(v * 0.70710678118654752f)));
                }
            }
        }
}

// ---------------------------------------------------------------------------
// K-split GEMM for N=256 outputs (Wo, W2): 512 threads = 8 waves =
// 4 output tiles (32x32) x 2 K-halves; f32 LDS combine; +res epilogue.
// ---------------------------------------------------------------------------
template<int KTOT>
__global__ __launch_bounds__(512) void gemm_ks(const __hip_bfloat16* __restrict__ A,
                                               const __hip_bfloat16* __restrict__ Wt,
                                               const float* __restrict__ bias,
                                               const float* __restrict__ res,
                                               float* __restrict__ outF,
                                               int N)
{
    constexpr int KH = KTOT / 2;
    __shared__ float red[4][64][17];
    const int tid = threadIdx.x;
    const int wv = tid >> 6, lane = tid & 63;
    const int t = wv & 3, ks = wv >> 2;
    const int wr = t >> 1, wc = t & 1;
    const int r0 = blockIdx.x * 64 + wr * 32;
    const int c0 = blockIdx.y * 64 + wc * 32;
    const int al = lane & 15, ah = lane >> 4;

    f32x4 acc[2][2] = {};
    const short8* Ap[2];
    const short8* Bp[2];
#pragma unroll
    for (int m = 0; m < 2; ++m)
        Ap[m] = (const short8*)(A + (size_t)(r0 + m*16 + al) * KTOT + ks*KH + ah * 8);
#pragma unroll
    for (int n = 0; n < 2; ++n)
        Bp[n] = (const short8*)(Wt + (size_t)(c0 + n*16 + al) * KTOT + ks*KH + ah * 8);

#pragma unroll 8
    for (int kt = 0; kt < KH/32; ++kt) {
        short8 af[2], bf[2];
#pragma unroll
        for (int m = 0; m < 2; ++m) af[m] = Ap[m][kt*4];
#pragma unroll
        for (int n = 0; n < 2; ++n) bf[n] = Bp[n][kt*4];
#pragma unroll
        for (int m = 0; m < 2; ++m)
#pragma unroll
            for (int n = 0; n < 2; ++n)
                acc[m][n] = __builtin_amdgcn_mfma_f32_16x16x32_bf16(
                    af[m], bf[n], acc[m][n], 0, 0, 0);
    }

    if (ks == 1) {
#pragma unroll
        for (int m = 0; m < 2; ++m)
#pragma unroll
            for (int n = 0; n < 2; ++n)
#pragma unroll
                for (int r = 0; r < 4; ++r)
                    red[t][lane][(m*2 + n)*4 + r] = acc[m][n][r];
    }
    __syncthreads();
    if (ks == 0) {
#pragma unroll
        for (int m = 0; m < 2; ++m)
#pragma unroll
            for (int n = 0; n < 2; ++n) {
                const int col = c0 + n*16 + al;
                const float bv = bias[col];
#pragma unroll
                for (int r = 0; r < 4; ++r) {
                    const int row = r0 + m*16 + ah*4 + r;
                    const float v = acc[m][n][r] + red[t][lane][(m*2 + n)*4 + r] + bv;
                    const size_t o = (size_t)row * N + col;
                    outF[o] = v + res[o];
                }
            }
    }
}

// ---------------------------------------------------------------------------
extern "C" void kernel_launch(void* const* d_in, const int* in_sizes, int n_in,
                              void* d_out, int out_size, void* d_ws, size_t ws_size,
                              hipStream_t stream)
{
    const float* x    = (const float*)d_in[0];
    const void*  mask = d_in[1];
    const float* ln1g = (const float*)d_in[2];
    const float* ln1b = (const float*)d_in[3];
    const float* ln2g = (const float*)d_in[4];
    const float* ln2b = (const float*)d_in[5];
    const float* Wq   = (const float*)d_in[6];
    const float* bq   = (const float*)d_in[7];
    const float* Wk   = (const float*)d_in[8];
    const float* bk   = (const float*)d_in[9];
    const float* Wv   = (const float*)d_in[10];
    const float* bv   = (const float*)d_in[11];
    const float* Wo   = (const float*)d_in[12];
    const float* bo   = (const float*)d_in[13];
    const float* W1   = (const float*)d_in[14];
    const float* b1   = (const float*)d_in[15];
    const float* W2   = (const float*)d_in[16];
    const float* b2   = (const float*)d_in[17];

    // Workspace (~44 MB), NO aliasing.
    char* w = (char*)d_ws;
    unsigned char* bmask  = (unsigned char*)(w + 4096);            // 1 MB
    __hip_bfloat16* qh    = (__hip_bfloat16*)(w + 4096 + (1 << 20));  // 2 MB
    __hip_bfloat16* kh    = qh  + (size_t)MROWS * HID;             // 2 MB
    __hip_bfloat16* vt    = kh  + (size_t)MROWS * HID;             // 2 MB
    __hip_bfloat16* nx    = vt  + (size_t)MROWS * HID;             // 2 MB
    __hip_bfloat16* attn_b= nx  + (size_t)MROWS * HID;             // 2 MB
    __hip_bfloat16* nx2   = attn_b + (size_t)MROWS * HID;          // 2 MB
    __hip_bfloat16* hbuf  = nx2 + (size_t)MROWS * HID;             // 8 MB
    float* x1             = (float*)(hbuf + (size_t)MROWS * 4*HID);// 4 MB
    __hip_bfloat16* Wtqkv = (__hip_bfloat16*)(x1 + (size_t)MROWS * HID);
    __hip_bfloat16* Wto   = Wtqkv + 196608;                        // [256][256]
    __hip_bfloat16* Wt1   = Wto + 65536;                           // [1024][256]
    __hip_bfloat16* Wt2   = Wt1 + 262144;                          // [256][1024]
    float* part_o         = (float*)(Wt2 + 262144);                // 16 MB
    float* part_l         = part_o + (size_t)8192 * 512;           // 512 KB
    float* ob   = (float*)d_out;

    pack_mask<<<MROWS, 256, 0, stream>>>(mask, bmask);
    tconv_all<<<768, 256, 0, stream>>>(Wq, Wk, Wv, Wo, W1, W2, Wtqkv, Wto, Wt1, Wt2);
    ln_wave<<<MROWS/4, 256, 0, stream>>>(x, ln1g, ln1b, nx);
    gemm_qkv<<<dim3(64,12), 256, 0, stream>>>(nx, Wtqkv, bq, bk, bv, qh, kh, vt);
    attn_part<<<2048, 256, 0, stream>>>(qh, kh, vt, (const unsigned*)bmask,
                                        part_o, part_l);
    attn_comb<<<4096, 256, 0, stream>>>(part_o, part_l, attn_b);
    gemm_ks<256><<<dim3(64,4), 512, 0, stream>>>(attn_b, Wto, bo, x, x1, HID);
    ln_wave<<<MROWS/4, 256, 0, stream>>>(x1, ln2g, ln2b, nx2);
    gemm_mfma<256,2><<<dim3(64,16), 256, 0, stream>>>(nx2, Wt1, b1, nullptr, nullptr, hbuf, 4*HID);
    gemm_ks<1024><<<dim3(64,4), 512, 0, stream>>>(hbuf, Wt2, b2, x1, ob, HID);
}